// Round 1
// 426.229 us; speedup vs baseline: 1.1912x; 1.1912x over previous
//
#include <hip/hip_runtime.h>

typedef __attribute__((ext_vector_type(8))) short bf16x8;
typedef __attribute__((ext_vector_type(4))) float f32x4;
typedef unsigned short u16;
typedef unsigned int u32;

#define MFMA __builtin_amdgcn_mfma_f32_16x16x32_bf16

static __device__ __forceinline__ float b2f(u16 u) {
    u32 x = ((u32)u) << 16;
    return __builtin_bit_cast(float, x);
}
static __device__ __forceinline__ u16 f2b(float f) {
    u32 u = __builtin_bit_cast(u32, f);
    u32 r = (u + 0x7fffu + ((u >> 16) & 1u)) >> 16;
    return (u16)r;
}
// async 16B/lane global->LDS DMA; lds base must be wave-uniform, lane i lands at +i*16
static __device__ __forceinline__ void async16(const u16* g, u16* l) {
    __builtin_amdgcn_global_load_lds(
        (const __attribute__((address_space(1))) u32*)g,
        (__attribute__((address_space(3))) u32*)l, 16, 0, 0);
}

// ---------------- x fp32 -> bf16 ----------------
__global__ __launch_bounds__(256) void xcast(const float* __restrict__ x, u16* __restrict__ xb) {
    size_t i = ((size_t)blockIdx.x * 256 + threadIdx.x) * 8;
    f32x4 f0 = *(const f32x4*)(x + i);
    f32x4 f1 = *(const f32x4*)(x + i + 4);
    bf16x8 v;
    v[0] = (short)f2b(f0[0]); v[1] = (short)f2b(f0[1]);
    v[2] = (short)f2b(f0[2]); v[3] = (short)f2b(f0[3]);
    v[4] = (short)f2b(f1[0]); v[5] = (short)f2b(f1[1]);
    v[6] = (short)f2b(f1[2]); v[7] = (short)f2b(f1[3]);
    *(bf16x8*)(xb + i) = v;
}

// ---------------- weight packing: WcatT[384][512], WoT[512][256] ----------------
__global__ void pack_w(const float* __restrict__ Wt, const float* __restrict__ Wp,
                       const float* __restrict__ Wg, const float* __restrict__ Wo,
                       u16* __restrict__ WcatT, u16* __restrict__ WoT) {
    int t = blockIdx.x * 256 + threadIdx.x;
    const int n1 = 384 * 512;
    if (t < n1) {
        int n = t >> 9, k = t & 511;
        float v;
        if (n < 64)       v = Wt[k * 64 + n];
        else if (n < 128) v = Wp[k * 64 + (n - 64)];
        else              v = Wg[k * 256 + (n - 128)];
        WcatT[t] = f2b(v);
    } else {
        int j = t - n1;
        if (j < 512 * 256) {
            int n = j >> 8, k = j & 255;
            WoT[j] = f2b(Wo[k * 512 + n]);
        }
    }
}

// ---------------- m97-style 128x128 GEMM core: A[M][K] bf16, Bt[N][K] bf16 ----------------
template <int K>
static __device__ __forceinline__ void gemm_core(const u16* __restrict__ A,
                                                 const u16* __restrict__ Bt,
                                                 int m0, int n0, int lda, int ldb,
                                                 f32x4 acc[4][4], u16* As, u16* Bs) {
    const int t = threadIdx.x;
    const int w = t >> 6, li = t & 15, quad = (t >> 4) & 3;
    const int wm = (w & 1) << 6, wn = (w >> 1) << 6;
#pragma unroll
    for (int mi = 0; mi < 4; mi++)
#pragma unroll
        for (int ni = 0; ni < 4; ni++) acc[mi][ni] = (f32x4)0.0f;
    const u16* ag = A + (size_t)(m0 + (t >> 2)) * lda + ((t & 3) << 3);
    const u16* bg = Bt + (size_t)(n0 + (t >> 2)) * ldb + ((t & 3) << 3);
    u16* asw = As + w * 512;
    u16* bsw = Bs + w * 512;
    for (int k0 = 0; k0 < K; k0 += 32) {
        __syncthreads();
        async16(ag + k0, asw);
        async16(ag + k0 + (size_t)64 * lda, asw + 2048);
        async16(bg + k0, bsw);
        async16(bg + k0 + (size_t)64 * ldb, bsw + 2048);
        __syncthreads();
        bf16x8 af[4], bfr[4];
#pragma unroll
        for (int mi = 0; mi < 4; mi++)
            af[mi] = *(const bf16x8*)(As + (wm + mi * 16 + li) * 32 + quad * 8);
#pragma unroll
        for (int ni = 0; ni < 4; ni++)
            bfr[ni] = *(const bf16x8*)(Bs + (wn + ni * 16 + li) * 32 + quad * 8);
#pragma unroll
        for (int mi = 0; mi < 4; mi++)
#pragma unroll
            for (int ni = 0; ni < 4; ni++)
                acc[mi][ni] = MFMA(af[mi], bfr[ni], acc[mi][ni], 0, 0, 0);
    }
    __syncthreads();  // allow epilogue to reuse As/Bs LDS
}

// per-wave LDS transpose epilogue -> coalesced 16B bf16 stores (64x64 quadrant)
static __device__ __forceinline__ void epi_bf16(const f32x4 acc[4][4], u16* ebuf,
                                                u16* __restrict__ outp, int ld,
                                                int row0, int col0) {
    const int t = threadIdx.x;
    const int li = t & 15, quad = (t >> 4) & 3;
#pragma unroll
    for (int mi = 0; mi < 4; mi++)
#pragma unroll
        for (int ni = 0; ni < 4; ni++)
#pragma unroll
            for (int r = 0; r < 4; r++)
                ebuf[(mi * 16 + quad * 4 + r) * 72 + ni * 16 + li] = f2b(acc[mi][ni][r]);
    const int rr = (t & 63) >> 3, cc = (t & 7) * 8;
#pragma unroll
    for (int j = 0; j < 8; j++) {
        int row = j * 8 + rr;
        bf16x8 v = *(const bf16x8*)(ebuf + row * 72 + cc);
        *(bf16x8*)(outp + (size_t)(row0 + row) * ld + col0 + cc) = v;
    }
}

// ---------------- proj: xb[65536x512] @ WcatT -> theta[*,64] + ppg[*,320] ----------------
__global__ __launch_bounds__(256) void proj_gemm(const u16* __restrict__ xb,
                                                 const u16* __restrict__ WcatT,
                                                 u16* __restrict__ theta,
                                                 u16* __restrict__ ppg) {
    __shared__ __attribute__((aligned(16))) u16 sbuf[18432];  // 36 KB
    u16* As = sbuf;
    u16* Bs = sbuf + 4096;
    int bm = blockIdx.x / 3, bn = blockIdx.x % 3;
    f32x4 acc[4][4];
    gemm_core<512>(xb, WcatT, bm * 128, bn * 128, 512, 512, acc, As, Bs);
    const int w = threadIdx.x >> 6;
    u16* ebuf = sbuf + w * 4608;
    int row0 = bm * 128 + (w & 1) * 64;
    int gcol = bn * 128 + (w >> 1) * 64;
    if (gcol < 64) epi_bf16(acc, ebuf, theta, 64, row0, 0);
    else           epi_bf16(acc, ebuf, ppg, 320, row0, gcol - 64);
}

// ---------------- maxpool phi: ppg cols 0..63 -> phi[b][1024][64] ----------------
__global__ void pool_phi(const u16* __restrict__ ppg, u16* __restrict__ phi) {
    int t = blockIdx.x * 256 + threadIdx.x;
    int c = t & 63;
    int pos = (t >> 6) & 1023;
    int b = t >> 16;
    int h2 = pos >> 5, w2 = pos & 31;
    size_t base = ((size_t)(b << 12) + h2 * 128 + w2 * 2) * 320 + c;
    float v0 = b2f(ppg[base]), v1 = b2f(ppg[base + 320]);
    float v2 = b2f(ppg[base + 320 * 64]), v3 = b2f(ppg[base + 320 * 65]);
    float m = fmaxf(fmaxf(v0, v1), fmaxf(v2, v3));
    phi[((size_t)(b << 10) + pos) * 64 + c] = f2b(m);
}

// ---------------- maxpool g, transposed: gT[b][256][1024] ----------------
__global__ void pool_gt(const u16* __restrict__ ppg, u16* __restrict__ gT) {
    __shared__ float tile[64][65];
    int bid = blockIdx.x;
    int b = bid >> 6;
    int rem = bid & 63;
    int c0 = (rem >> 4) * 64;
    int pos0 = (rem & 15) * 64;
    int t = threadIdx.x;
#pragma unroll
    for (int i = 0; i < 16; i++) {
        int o = t + i * 256;
        int cl = o & 63, pl = o >> 6;
        int pos = pos0 + pl;
        int h2 = pos >> 5, w2 = pos & 31;
        size_t base = ((size_t)(b << 12) + h2 * 128 + w2 * 2) * 320 + 64 + c0 + cl;
        float v0 = b2f(ppg[base]), v1 = b2f(ppg[base + 320]);
        float v2 = b2f(ppg[base + 320 * 64]), v3 = b2f(ppg[base + 320 * 65]);
        tile[pl][cl] = fmaxf(fmaxf(v0, v1), fmaxf(v2, v3));
    }
    __syncthreads();
    int cl = t >> 2, ch = t & 3;
    u16 valbuf[16] __attribute__((aligned(16)));
#pragma unroll
    for (int j = 0; j < 16; j++) valbuf[j] = f2b(tile[ch * 16 + j][cl]);
    u16* dst = gT + ((size_t)b * 256 + c0 + cl) * 1024 + pos0 + ch * 16;
    *(uint4*)(dst) = *(const uint4*)(valbuf);
    *(uint4*)(dst + 8) = *(const uint4*)(valbuf + 8);
}

// ---------------- fused attention, QBLK=64, wave-owns-16q, online softmax ----------------
// Per block: 64 q rows (4 waves x 16 q). Loop over 16 chunks of 64 keys:
//   stage phi[64kb][64d] (8 KiB) + gT[256v][64k] (32 KiB) via DMA, XOR-chunk-swizzled.
//   scores SWAPPED: S^T = mfma(A=phi,B=theta) -> q lands on lane&15 (softmax state scalar/lane)
//   online softmax with defer-max THR=8 (T13), P -> wave-private LDS bounce (2 KiB) -> B-frags
//   PV: O^T = mfma(A=g, B=P), q stays on lane&15 -> final 1/sum is scalar/lane.
__global__ __launch_bounds__(256, 3) void attn_fused(const u16* __restrict__ theta,
                                                     const u16* __restrict__ phi,
                                                     const u16* __restrict__ gT,
                                                     u16* __restrict__ tmp) {
    __shared__ __attribute__((aligned(16))) u16 lds[24576];  // 48 KiB
    u16* stgP = lds;            // [64 key][64 d] swizzled, 8 KiB
    u16* stgG = lds + 4096;     // [256 v][64 k] swizzled, 32 KiB
    u16* pbuf = lds + 20480;    // 4 x wave-private [16 q][64 k] swizzled, 8 KiB

    int bid = blockIdx.x;
    int swz = (bid & 7) * 128 + (bid >> 3);   // XCD-aware, bijective (1024 % 8 == 0)
    int b = swz >> 6;
    int q0 = (swz & 63) << 6;
    const int t = threadIdx.x;
    const int w = t >> 6, li = t & 15, quad = (t >> 4) & 3;

    // theta B-frags for this wave's 16 q rows (q = q0 + w*16 + li)
    const u16* thp = theta + (((size_t)(b << 12) + q0 + w * 16 + li) << 6) + quad * 8;
    bf16x8 tq0 = *(const bf16x8*)thp;
    bf16x8 tq1 = *(const bf16x8*)(thp + 32);

    // DMA source swizzle: LDS slot (row=t>>3 (+32j), pos=t&7) <- global chunk pos^(row&7)
    const int srow = t >> 3;
    const int sc = (t & 7) ^ (srow & 7);
    const u16* phisrc = phi + ((size_t)(b << 10) + srow) * 64 + sc * 8;
    const u16* gsrc = gT + ((size_t)(b << 8) + srow) * 1024 + sc * 8;
    u16* pb = pbuf + w * 1024;

    f32x4 o[16];
#pragma unroll
    for (int ni = 0; ni < 16; ni++) o[ni] = (f32x4)0.0f;
    float m = -3.0e38f, sum = 0.0f;

    for (int kc = 0; kc < 16; kc++) {
        __syncthreads();
        // stage phi chunk (2 shots) + gT chunk (8 shots)
        async16(phisrc + (size_t)(kc * 64) * 64, stgP + w * 512);
        async16(phisrc + (size_t)(kc * 64 + 32) * 64, stgP + 2048 + w * 512);
#pragma unroll
        for (int j = 0; j < 8; j++)
            async16(gsrc + (size_t)(j * 32) * 1024 + kc * 64, stgG + j * 2048 + w * 512);
        __syncthreads();

        // ---- scores (swapped): sacc[nf] = S^T[key = nf*16+quad*4+r][q = li] ----
        f32x4 sacc[4];
#pragma unroll
        for (int nf = 0; nf < 4; nf++) sacc[nf] = (f32x4)0.0f;
#pragma unroll
        for (int nf = 0; nf < 4; nf++) {
            int row = nf * 16 + li;
            int p0 = quad ^ (li & 7);
            int p1 = (4 + quad) ^ (li & 7);
            bf16x8 f0 = *(const bf16x8*)(stgP + row * 64 + p0 * 8);
            bf16x8 f1 = *(const bf16x8*)(stgP + row * 64 + p1 * 8);
            sacc[nf] = MFMA(f0, tq0, sacc[nf], 0, 0, 0);
            sacc[nf] = MFMA(f1, tq1, sacc[nf], 0, 0, 0);
        }

        // ---- online softmax; state per q, q == li for all 4 quad-replicas ----
        float mc = sacc[0][0];
#pragma unroll
        for (int nf = 0; nf < 4; nf++)
#pragma unroll
            for (int r = 0; r < 4; r++) mc = fmaxf(mc, sacc[nf][r]);
        mc = fmaxf(mc, __shfl_xor(mc, 16, 64));
        mc = fmaxf(mc, __shfl_xor(mc, 32, 64));
        if (!__all(mc <= m + 8.0f)) {   // defer-max: rescale only on real growth
            float nm = fmaxf(m, mc);
            float f = __expf(m - nm);
            sum *= f;
#pragma unroll
            for (int ni = 0; ni < 16; ni++)
#pragma unroll
                for (int r = 0; r < 4; r++) o[ni][r] *= f;
            m = nm;
        }
        float p[16];
        float s = 0.0f;
#pragma unroll
        for (int nf = 0; nf < 4; nf++)
#pragma unroll
            for (int r = 0; r < 4; r++) {
                float e = __expf(sacc[nf][r] - m);
                p[nf * 4 + r] = e;
                s += e;
            }
        s += __shfl_xor(s, 16, 64);
        s += __shfl_xor(s, 32, 64);
        sum += s;

        // ---- P -> wave-private LDS (bf16 pairs, XOR chunk swizzle) ----
#pragma unroll
        for (int nf = 0; nf < 4; nf++) {
            int cc = nf * 2 + (quad >> 1);
            int pos = cc ^ (li & 7);
            u32* dst = (u32*)(pb + li * 64 + pos * 8 + (quad & 1) * 4);
            dst[0] = (u32)f2b(p[nf * 4 + 0]) | ((u32)f2b(p[nf * 4 + 1]) << 16);
            dst[1] = (u32)f2b(p[nf * 4 + 2]) | ((u32)f2b(p[nf * 4 + 3]) << 16);
        }

        // ---- PV: o[ni] += mfma(A=g[v][k], B=P[q][k]); same-wave LDS RAW is ordered ----
#pragma unroll
        for (int w2 = 0; w2 < 2; w2++) {
            int pos8 = ((w2 * 4 + quad) ^ (li & 7)) * 8;
            bf16x8 pf = *(const bf16x8*)(pb + li * 64 + pos8);
#pragma unroll
            for (int ni = 0; ni < 16; ni++) {
                bf16x8 gf = *(const bf16x8*)(stgG + (ni * 16 + li) * 64 + pos8);
                o[ni] = MFMA(gf, pf, o[ni], 0, 0, 0);
            }
        }
    }

    // ---- normalize (1/sum is scalar per lane: q == li) ----
    float inv = 1.0f / sum;
#pragma unroll
    for (int ni = 0; ni < 16; ni++)
#pragma unroll
        for (int r = 0; r < 4; r++) o[ni][r] *= inv;

    // ---- epilogue: per-wave transpose O^T[v][q] -> tmp[q][256v], coalesced 16B stores ----
    __syncthreads();  // all waves done reading stgP/stgG
    u16* eb = lds + w * 4224;  // 16 q rows x 264 elems (padded)
#pragma unroll
    for (int ni = 0; ni < 16; ni++) {
        u32* d = (u32*)(eb + li * 264 + ni * 16 + quad * 4);
        d[0] = (u32)f2b(o[ni][0]) | ((u32)f2b(o[ni][1]) << 16);
        d[1] = (u32)f2b(o[ni][2]) | ((u32)f2b(o[ni][3]) << 16);
    }
    const int lane = t & 63;
#pragma unroll
    for (int pss = 0; pss < 8; pss++) {
        int row = pss * 2 + (lane >> 5);
        bf16x8 v = *(const bf16x8*)(eb + row * 264 + (lane & 31) * 8);
        *(bf16x8*)(tmp + ((size_t)(b << 12) + q0 + w * 16 + row) * 256 + (lane & 31) * 8) = v;
    }
}

// ---------------- out: tmp[65536x256] @ WoT + gamma*o + x (fp32) ----------------
__global__ __launch_bounds__(256) void out_gemm(const u16* __restrict__ tmp,
                                                const u16* __restrict__ WoT,
                                                const float* __restrict__ x,
                                                const float* __restrict__ gamma_p,
                                                float* __restrict__ out) {
    __shared__ __attribute__((aligned(16))) u16 sbuf[18432];
    u16* As = sbuf;
    u16* Bs = sbuf + 4096;
    int bm = blockIdx.x >> 2, bn = blockIdx.x & 3;
    f32x4 acc[4][4];
    gemm_core<256>(tmp, WoT, bm * 128, bn * 128, 256, 256, acc, As, Bs);
    float gamma = gamma_p[0];
    const int t = threadIdx.x;
    const int w = t >> 6, li = t & 15, quad = (t >> 4) & 3;
    int row0 = bm * 128 + (w & 1) * 64;
    int col0 = bn * 128 + (w >> 1) * 64;
    float* fb = (float*)sbuf + w * 2176;  // 32 x 68 fp32 per wave
    const int rr = (t & 63) >> 4, ccv = (t & 15) * 4;
#pragma unroll
    for (int half = 0; half < 2; half++) {
#pragma unroll
        for (int mi = 0; mi < 2; mi++)
#pragma unroll
            for (int ni = 0; ni < 4; ni++)
#pragma unroll
                for (int r = 0; r < 4; r++)
                    fb[(mi * 16 + quad * 4 + r) * 68 + ni * 16 + li] =
                        acc[half * 2 + mi][ni][r];
#pragma unroll
        for (int j = 0; j < 8; j++) {
            int row = j * 4 + rr;
            f32x4 v = *(const f32x4*)(fb + row * 68 + ccv);
            size_t go = (size_t)(row0 + half * 32 + row) * 512 + col0 + ccv;
            f32x4 xv = *(const f32x4*)(x + go);
#pragma unroll
            for (int e = 0; e < 4; e++) v[e] = gamma * v[e] + xv[e];
            *(f32x4*)(out + go) = v;
        }
    }
}

extern "C" void kernel_launch(void* const* d_in, const int* in_sizes, int n_in,
                              void* d_out, int out_size, void* d_ws, size_t ws_size,
                              hipStream_t stream) {
    (void)in_sizes; (void)n_in; (void)out_size; (void)ws_size;
    const float* x  = (const float*)d_in[0];
    const float* Wt = (const float*)d_in[1];
    const float* Wp = (const float*)d_in[2];
    const float* Wg = (const float*)d_in[3];
    const float* Wo = (const float*)d_in[4];
    const float* gm = (const float*)d_in[5];
    float* out = (float*)d_out;

    char* ws = (char*)d_ws;
    size_t off = 0;
    u16* WcatT = (u16*)(ws + off); off += (size_t)384 * 512 * 2;
    u16* WoT   = (u16*)(ws + off); off += (size_t)512 * 256 * 2;
    u16* xb    = (u16*)(ws + off); off += (size_t)65536 * 512 * 2;   // 64 MiB
    u16* theta = (u16*)(ws + off); off += (size_t)65536 * 64 * 2;    // 8 MiB
    u16* ppg   = (u16*)(ws + off); off += (size_t)65536 * 320 * 2;   // 40 MiB
    // aliases: xb dead after proj -> phi/gT live there; ppg dead after pools -> tmp
    u16* phi = xb;                                   // 2 MiB
    u16* gT  = xb + (size_t)16 * 1024 * 64;          // 8 MiB
    u16* tmp = ppg;                                  // 32 MiB

    pack_w<<<1280, 256, 0, stream>>>(Wt, Wp, Wg, Wo, WcatT, WoT);
    xcast<<<16384, 256, 0, stream>>>(x, xb);
    proj_gemm<<<1536, 256, 0, stream>>>(xb, WcatT, theta, ppg);
    pool_phi<<<4096, 256, 0, stream>>>(ppg, phi);
    pool_gt<<<1024, 256, 0, stream>>>(ppg, gT);
    attn_fused<<<1024, 256, 0, stream>>>(theta, phi, gT, tmp);
    out_gemm<<<2048, 256, 0, stream>>>(tmp, WoT, x, gm, out);
}

// Round 2
// 410.483 us; speedup vs baseline: 1.2369x; 1.0384x over previous
//
#include <hip/hip_runtime.h>

typedef __attribute__((ext_vector_type(8))) short bf16x8;
typedef __attribute__((ext_vector_type(4))) float f32x4;
typedef unsigned short u16;
typedef unsigned int u32;

#define MFMA __builtin_amdgcn_mfma_f32_16x16x32_bf16

static __device__ __forceinline__ float b2f(u16 u) {
    u32 x = ((u32)u) << 16;
    return __builtin_bit_cast(float, x);
}
static __device__ __forceinline__ u16 f2b(float f) {
    u32 u = __builtin_bit_cast(u32, f);
    u32 r = (u + 0x7fffu + ((u >> 16) & 1u)) >> 16;
    return (u16)r;
}
// async 16B/lane global->LDS DMA; lds base must be wave-uniform, lane i lands at +i*16
static __device__ __forceinline__ void async16(const u16* g, u16* l) {
    __builtin_amdgcn_global_load_lds(
        (const __attribute__((address_space(1))) u32*)g,
        (__attribute__((address_space(3))) u32*)l, 16, 0, 0);
}

// ---------------- x fp32 -> bf16 ----------------
__global__ __launch_bounds__(256) void xcast(const float* __restrict__ x, u16* __restrict__ xb) {
    size_t i = ((size_t)blockIdx.x * 256 + threadIdx.x) * 8;
    f32x4 f0 = *(const f32x4*)(x + i);
    f32x4 f1 = *(const f32x4*)(x + i + 4);
    bf16x8 v;
    v[0] = (short)f2b(f0[0]); v[1] = (short)f2b(f0[1]);
    v[2] = (short)f2b(f0[2]); v[3] = (short)f2b(f0[3]);
    v[4] = (short)f2b(f1[0]); v[5] = (short)f2b(f1[1]);
    v[6] = (short)f2b(f1[2]); v[7] = (short)f2b(f1[3]);
    *(bf16x8*)(xb + i) = v;
}

// ---------------- weight packing: WcatT[384][512], WoT[512][256] ----------------
__global__ void pack_w(const float* __restrict__ Wt, const float* __restrict__ Wp,
                       const float* __restrict__ Wg, const float* __restrict__ Wo,
                       u16* __restrict__ WcatT, u16* __restrict__ WoT) {
    int t = blockIdx.x * 256 + threadIdx.x;
    const int n1 = 384 * 512;
    if (t < n1) {
        int n = t >> 9, k = t & 511;
        float v;
        if (n < 64)       v = Wt[k * 64 + n];
        else if (n < 128) v = Wp[k * 64 + (n - 64)];
        else              v = Wg[k * 256 + (n - 128)];
        WcatT[t] = f2b(v);
    } else {
        int j = t - n1;
        if (j < 512 * 256) {
            int n = j >> 8, k = j & 255;
            WoT[j] = f2b(Wo[k * 512 + n]);
        }
    }
}

// ---------------- m97-style 128x128 GEMM core: A[M][K] bf16, Bt[N][K] bf16 ----------------
template <int K>
static __device__ __forceinline__ void gemm_core(const u16* __restrict__ A,
                                                 const u16* __restrict__ Bt,
                                                 int m0, int n0, int lda, int ldb,
                                                 f32x4 acc[4][4], u16* As, u16* Bs) {
    const int t = threadIdx.x;
    const int w = t >> 6, li = t & 15, quad = (t >> 4) & 3;
    const int wm = (w & 1) << 6, wn = (w >> 1) << 6;
#pragma unroll
    for (int mi = 0; mi < 4; mi++)
#pragma unroll
        for (int ni = 0; ni < 4; ni++) acc[mi][ni] = (f32x4)0.0f;
    const u16* ag = A + (size_t)(m0 + (t >> 2)) * lda + ((t & 3) << 3);
    const u16* bg = Bt + (size_t)(n0 + (t >> 2)) * ldb + ((t & 3) << 3);
    u16* asw = As + w * 512;
    u16* bsw = Bs + w * 512;
    for (int k0 = 0; k0 < K; k0 += 32) {
        __syncthreads();
        async16(ag + k0, asw);
        async16(ag + k0 + (size_t)64 * lda, asw + 2048);
        async16(bg + k0, bsw);
        async16(bg + k0 + (size_t)64 * ldb, bsw + 2048);
        __syncthreads();
        bf16x8 af[4], bfr[4];
#pragma unroll
        for (int mi = 0; mi < 4; mi++)
            af[mi] = *(const bf16x8*)(As + (wm + mi * 16 + li) * 32 + quad * 8);
#pragma unroll
        for (int ni = 0; ni < 4; ni++)
            bfr[ni] = *(const bf16x8*)(Bs + (wn + ni * 16 + li) * 32 + quad * 8);
#pragma unroll
        for (int mi = 0; mi < 4; mi++)
#pragma unroll
            for (int ni = 0; ni < 4; ni++)
                acc[mi][ni] = MFMA(af[mi], bfr[ni], acc[mi][ni], 0, 0, 0);
    }
    __syncthreads();  // allow epilogue to reuse As/Bs LDS
}

// per-wave LDS transpose epilogue -> coalesced 16B bf16 stores (64x64 quadrant)
static __device__ __forceinline__ void epi_bf16(const f32x4 acc[4][4], u16* ebuf,
                                                u16* __restrict__ outp, int ld,
                                                int row0, int col0) {
    const int t = threadIdx.x;
    const int li = t & 15, quad = (t >> 4) & 3;
#pragma unroll
    for (int mi = 0; mi < 4; mi++)
#pragma unroll
        for (int ni = 0; ni < 4; ni++)
#pragma unroll
            for (int r = 0; r < 4; r++)
                ebuf[(mi * 16 + quad * 4 + r) * 72 + ni * 16 + li] = f2b(acc[mi][ni][r]);
    const int rr = (t & 63) >> 3, cc = (t & 7) * 8;
#pragma unroll
    for (int j = 0; j < 8; j++) {
        int row = j * 8 + rr;
        bf16x8 v = *(const bf16x8*)(ebuf + row * 72 + cc);
        *(bf16x8*)(outp + (size_t)(row0 + row) * ld + col0 + cc) = v;
    }
}

// ---------------- proj: xb[65536x512] @ WcatT -> theta[*,64] + ppg[*,320] ----------------
__global__ __launch_bounds__(256) void proj_gemm(const u16* __restrict__ xb,
                                                 const u16* __restrict__ WcatT,
                                                 u16* __restrict__ theta,
                                                 u16* __restrict__ ppg) {
    __shared__ __attribute__((aligned(16))) u16 sbuf[18432];  // 36 KB
    u16* As = sbuf;
    u16* Bs = sbuf + 4096;
    int bm = blockIdx.x / 3, bn = blockIdx.x % 3;
    f32x4 acc[4][4];
    gemm_core<512>(xb, WcatT, bm * 128, bn * 128, 512, 512, acc, As, Bs);
    const int w = threadIdx.x >> 6;
    u16* ebuf = sbuf + w * 4608;
    int row0 = bm * 128 + (w & 1) * 64;
    int gcol = bn * 128 + (w >> 1) * 64;
    if (gcol < 64) epi_bf16(acc, ebuf, theta, 64, row0, 0);
    else           epi_bf16(acc, ebuf, ppg, 320, row0, gcol - 64);
}

// ---------------- maxpool phi: ppg cols 0..63 -> phi[b][1024][64] ----------------
__global__ void pool_phi(const u16* __restrict__ ppg, u16* __restrict__ phi) {
    int t = blockIdx.x * 256 + threadIdx.x;
    int c = t & 63;
    int pos = (t >> 6) & 1023;
    int b = t >> 16;
    int h2 = pos >> 5, w2 = pos & 31;
    size_t base = ((size_t)(b << 12) + h2 * 128 + w2 * 2) * 320 + c;
    float v0 = b2f(ppg[base]), v1 = b2f(ppg[base + 320]);
    float v2 = b2f(ppg[base + 320 * 64]), v3 = b2f(ppg[base + 320 * 65]);
    float m = fmaxf(fmaxf(v0, v1), fmaxf(v2, v3));
    phi[((size_t)(b << 10) + pos) * 64 + c] = f2b(m);
}

// ---------------- maxpool g, transposed: gT[b][256][1024] ----------------
__global__ void pool_gt(const u16* __restrict__ ppg, u16* __restrict__ gT) {
    __shared__ float tile[64][65];
    int bid = blockIdx.x;
    int b = bid >> 6;
    int rem = bid & 63;
    int c0 = (rem >> 4) * 64;
    int pos0 = (rem & 15) * 64;
    int t = threadIdx.x;
#pragma unroll
    for (int i = 0; i < 16; i++) {
        int o = t + i * 256;
        int cl = o & 63, pl = o >> 6;
        int pos = pos0 + pl;
        int h2 = pos >> 5, w2 = pos & 31;
        size_t base = ((size_t)(b << 12) + h2 * 128 + w2 * 2) * 320 + 64 + c0 + cl;
        float v0 = b2f(ppg[base]), v1 = b2f(ppg[base + 320]);
        float v2 = b2f(ppg[base + 320 * 64]), v3 = b2f(ppg[base + 320 * 65]);
        tile[pl][cl] = fmaxf(fmaxf(v0, v1), fmaxf(v2, v3));
    }
    __syncthreads();
    int cl = t >> 2, ch = t & 3;
    u16 valbuf[16] __attribute__((aligned(16)));
#pragma unroll
    for (int j = 0; j < 16; j++) valbuf[j] = f2b(tile[ch * 16 + j][cl]);
    u16* dst = gT + ((size_t)b * 256 + c0 + cl) * 1024 + pos0 + ch * 16;
    *(uint4*)(dst) = *(const uint4*)(valbuf);
    *(uint4*)(dst + 8) = *(const uint4*)(valbuf + 8);
}

// ---------------- fused attention, QBLK=128, wave-owns-32q (2 x 16q groups) ----------------
// Per block: 128 q rows (4 waves x 32 q). Loop over 16 chunks of 64 keys:
//   stage phi[64kb][64d] (8 KiB) + gT[256v][64k] (32 KiB) via DMA, XOR-chunk-swizzled.
//   scores SWAPPED: S^T = mfma(A=phi,B=theta_qg) -> q on lane&15; phi frags SHARED by both qg.
//   online softmax per qg (defer-max THR=8); P -> wave-private LDS (2 KiB per qg).
//   PV: O^T = mfma(A=g, B=P_qg); each g frag read once, used by BOTH qg -> 2x MFMA/LDS-read.
__global__ __launch_bounds__(256, 2) void attn_fused(const u16* __restrict__ theta,
                                                     const u16* __restrict__ phi,
                                                     const u16* __restrict__ gT,
                                                     u16* __restrict__ tmp) {
    __shared__ __attribute__((aligned(16))) u16 lds[28672];  // 56 KiB
    u16* stgP = lds;            // [64 key][64 d] swizzled, 8 KiB
    u16* stgG = lds + 4096;     // [256 v][64 k] swizzled, 32 KiB
    u16* pbuf = lds + 20480;    // 4 waves x 2 qg x [16 q][64 k] swizzled, 16 KiB

    int bid = blockIdx.x;
    int swz = (bid & 7) * 64 + (bid >> 3);   // XCD-aware, bijective (512 % 8 == 0)
    int b = swz >> 5;
    int q0 = (swz & 31) << 7;
    const int t = threadIdx.x;
    const int w = t >> 6, li = t & 15, quad = (t >> 4) & 3;

    // theta B-frags for this wave's 32 q rows (q = q0 + w*32 + qg*16 + li)
    const u16* thp = theta + (((size_t)(b << 12) + q0 + w * 32 + li) << 6) + quad * 8;
    bf16x8 tq[2][2];
    tq[0][0] = *(const bf16x8*)thp;
    tq[0][1] = *(const bf16x8*)(thp + 32);
    tq[1][0] = *(const bf16x8*)(thp + (16 << 6));
    tq[1][1] = *(const bf16x8*)(thp + (16 << 6) + 32);

    // DMA source swizzle: LDS slot (row=t>>3 (+32j), pos=t&7) <- global chunk pos^(row&7)
    const int srow = t >> 3;
    const int sc = (t & 7) ^ (srow & 7);
    const u16* phisrc = phi + ((size_t)(b << 10) + srow) * 64 + sc * 8;
    const u16* gsrc = gT + ((size_t)(b << 8) + srow) * 1024 + sc * 8;
    u16* pbq[2] = {pbuf + (w * 2 + 0) * 1024, pbuf + (w * 2 + 1) * 1024};

    f32x4 o[2][16];
#pragma unroll
    for (int qg = 0; qg < 2; qg++)
#pragma unroll
        for (int ni = 0; ni < 16; ni++) o[qg][ni] = (f32x4)0.0f;
    float m[2] = {-3.0e38f, -3.0e38f}, sum[2] = {0.0f, 0.0f};

    for (int kc = 0; kc < 16; kc++) {
        __syncthreads();
        // stage phi chunk (2 shots) + gT chunk (8 shots)
        async16(phisrc + (size_t)(kc * 64) * 64, stgP + w * 512);
        async16(phisrc + (size_t)(kc * 64 + 32) * 64, stgP + 2048 + w * 512);
#pragma unroll
        for (int j = 0; j < 8; j++)
            async16(gsrc + (size_t)(j * 32) * 1024 + kc * 64, stgG + j * 2048 + w * 512);
        __syncthreads();

        // ---- scores (swapped): sacc[qg][nf] = S^T[key = nf*16+quad*4+r][q = li] ----
        // phi A-frags shared across both q-groups
        f32x4 sacc[2][4];
#pragma unroll
        for (int qg = 0; qg < 2; qg++)
#pragma unroll
            for (int nf = 0; nf < 4; nf++) sacc[qg][nf] = (f32x4)0.0f;
#pragma unroll
        for (int nf = 0; nf < 4; nf++) {
            int row = nf * 16 + li;
            int p0 = quad ^ (li & 7);
            int p1 = (4 + quad) ^ (li & 7);
            bf16x8 f0 = *(const bf16x8*)(stgP + row * 64 + p0 * 8);
            bf16x8 f1 = *(const bf16x8*)(stgP + row * 64 + p1 * 8);
            sacc[0][nf] = MFMA(f0, tq[0][0], sacc[0][nf], 0, 0, 0);
            sacc[0][nf] = MFMA(f1, tq[0][1], sacc[0][nf], 0, 0, 0);
            sacc[1][nf] = MFMA(f0, tq[1][0], sacc[1][nf], 0, 0, 0);
            sacc[1][nf] = MFMA(f1, tq[1][1], sacc[1][nf], 0, 0, 0);
        }

        // ---- online softmax per qg; state per q, q == li for all 4 quad-replicas ----
#pragma unroll
        for (int qg = 0; qg < 2; qg++) {
            float mc = sacc[qg][0][0];
#pragma unroll
            for (int nf = 0; nf < 4; nf++)
#pragma unroll
                for (int r = 0; r < 4; r++) mc = fmaxf(mc, sacc[qg][nf][r]);
            mc = fmaxf(mc, __shfl_xor(mc, 16, 64));
            mc = fmaxf(mc, __shfl_xor(mc, 32, 64));
            if (!__all(mc <= m[qg] + 8.0f)) {   // defer-max: rescale only on real growth
                float nm = fmaxf(m[qg], mc);
                float f = __expf(m[qg] - nm);
                sum[qg] *= f;
#pragma unroll
                for (int ni = 0; ni < 16; ni++)
#pragma unroll
                    for (int r = 0; r < 4; r++) o[qg][ni][r] *= f;
                m[qg] = nm;
            }
            float p[16];
            float s = 0.0f;
#pragma unroll
            for (int nf = 0; nf < 4; nf++)
#pragma unroll
                for (int r = 0; r < 4; r++) {
                    float e = __expf(sacc[qg][nf][r] - m[qg]);
                    p[nf * 4 + r] = e;
                    s += e;
                }
            s += __shfl_xor(s, 16, 64);
            s += __shfl_xor(s, 32, 64);
            sum[qg] += s;

            // ---- P -> wave-private LDS (bf16 pairs, XOR chunk swizzle) ----
            u16* pb = pbq[qg];
#pragma unroll
            for (int nf = 0; nf < 4; nf++) {
                int cc = nf * 2 + (quad >> 1);
                int pos = cc ^ (li & 7);
                u32* dst = (u32*)(pb + li * 64 + pos * 8 + (quad & 1) * 4);
                dst[0] = (u32)f2b(p[nf * 4 + 0]) | ((u32)f2b(p[nf * 4 + 1]) << 16);
                dst[1] = (u32)f2b(p[nf * 4 + 2]) | ((u32)f2b(p[nf * 4 + 3]) << 16);
            }
        }

        // ---- PV: o[qg][ni] += mfma(A=g, B=P_qg); g frag read once, used twice ----
#pragma unroll
        for (int w2 = 0; w2 < 2; w2++) {
            int pos8 = ((w2 * 4 + quad) ^ (li & 7)) * 8;
            bf16x8 pf0 = *(const bf16x8*)(pbq[0] + li * 64 + pos8);
            bf16x8 pf1 = *(const bf16x8*)(pbq[1] + li * 64 + pos8);
#pragma unroll
            for (int ni = 0; ni < 16; ni++) {
                bf16x8 gf = *(const bf16x8*)(stgG + (ni * 16 + li) * 64 + pos8);
                o[0][ni] = MFMA(gf, pf0, o[0][ni], 0, 0, 0);
                o[1][ni] = MFMA(gf, pf1, o[1][ni], 0, 0, 0);
            }
        }
    }

    // ---- normalize (1/sum is scalar per lane: q == li) ----
    float inv[2] = {1.0f / sum[0], 1.0f / sum[1]};
#pragma unroll
    for (int qg = 0; qg < 2; qg++)
#pragma unroll
        for (int ni = 0; ni < 16; ni++)
#pragma unroll
            for (int r = 0; r < 4; r++) o[qg][ni][r] *= inv[qg];

    // ---- epilogue: per-wave transpose O^T[v][q] -> tmp[q][256v], coalesced 16B stores ----
    __syncthreads();  // all waves done reading stgP/stgG
    u16* eb = lds + w * 4224;  // 16 q rows x 264 elems (padded), reused per qg
    const int lane = t & 63;
#pragma unroll
    for (int qg = 0; qg < 2; qg++) {
#pragma unroll
        for (int ni = 0; ni < 16; ni++) {
            u32* d = (u32*)(eb + li * 264 + ni * 16 + quad * 4);
            d[0] = (u32)f2b(o[qg][ni][0]) | ((u32)f2b(o[qg][ni][1]) << 16);
            d[1] = (u32)f2b(o[qg][ni][2]) | ((u32)f2b(o[qg][ni][3]) << 16);
        }
#pragma unroll
        for (int pss = 0; pss < 8; pss++) {
            int row = pss * 2 + (lane >> 5);
            bf16x8 v = *(const bf16x8*)(eb + row * 264 + (lane & 31) * 8);
            *(bf16x8*)(tmp + ((size_t)(b << 12) + q0 + w * 32 + qg * 16 + row) * 256 +
                       (lane & 31) * 8) = v;
        }
    }
}

// ---------------- out: tmp[65536x256] @ WoT + gamma*o + x (fp32) ----------------
__global__ __launch_bounds__(256) void out_gemm(const u16* __restrict__ tmp,
                                                const u16* __restrict__ WoT,
                                                const float* __restrict__ x,
                                                const float* __restrict__ gamma_p,
                                                float* __restrict__ out) {
    __shared__ __attribute__((aligned(16))) u16 sbuf[18432];
    u16* As = sbuf;
    u16* Bs = sbuf + 4096;
    int bm = blockIdx.x >> 2, bn = blockIdx.x & 3;
    f32x4 acc[4][4];
    gemm_core<256>(tmp, WoT, bm * 128, bn * 128, 256, 256, acc, As, Bs);
    float gamma = gamma_p[0];
    const int t = threadIdx.x;
    const int w = t >> 6, li = t & 15, quad = (t >> 4) & 3;
    int row0 = bm * 128 + (w & 1) * 64;
    int col0 = bn * 128 + (w >> 1) * 64;
    float* fb = (float*)sbuf + w * 2176;  // 32 x 68 fp32 per wave
    const int rr = (t & 63) >> 4, ccv = (t & 15) * 4;
#pragma unroll
    for (int half = 0; half < 2; half++) {
#pragma unroll
        for (int mi = 0; mi < 2; mi++)
#pragma unroll
            for (int ni = 0; ni < 4; ni++)
#pragma unroll
                for (int r = 0; r < 4; r++)
                    fb[(mi * 16 + quad * 4 + r) * 68 + ni * 16 + li] =
                        acc[half * 2 + mi][ni][r];
#pragma unroll
        for (int j = 0; j < 8; j++) {
            int row = j * 4 + rr;
            f32x4 v = *(const f32x4*)(fb + row * 68 + ccv);
            size_t go = (size_t)(row0 + half * 32 + row) * 512 + col0 + ccv;
            f32x4 xv = *(const f32x4*)(x + go);
#pragma unroll
            for (int e = 0; e < 4; e++) v[e] = gamma * v[e] + xv[e];
            *(f32x4*)(out + go) = v;
        }
    }
}

extern "C" void kernel_launch(void* const* d_in, const int* in_sizes, int n_in,
                              void* d_out, int out_size, void* d_ws, size_t ws_size,
                              hipStream_t stream) {
    (void)in_sizes; (void)n_in; (void)out_size; (void)ws_size;
    const float* x  = (const float*)d_in[0];
    const float* Wt = (const float*)d_in[1];
    const float* Wp = (const float*)d_in[2];
    const float* Wg = (const float*)d_in[3];
    const float* Wo = (const float*)d_in[4];
    const float* gm = (const float*)d_in[5];
    float* out = (float*)d_out;

    char* ws = (char*)d_ws;
    size_t off = 0;
    u16* WcatT = (u16*)(ws + off); off += (size_t)384 * 512 * 2;
    u16* WoT   = (u16*)(ws + off); off += (size_t)512 * 256 * 2;
    u16* xb    = (u16*)(ws + off); off += (size_t)65536 * 512 * 2;   // 64 MiB
    u16* theta = (u16*)(ws + off); off += (size_t)65536 * 64 * 2;    // 8 MiB
    u16* ppg   = (u16*)(ws + off); off += (size_t)65536 * 320 * 2;   // 40 MiB
    // aliases: xb dead after proj -> phi/gT live there; ppg dead after pools -> tmp
    u16* phi = xb;                                   // 2 MiB
    u16* gT  = xb + (size_t)16 * 1024 * 64;          // 8 MiB
    u16* tmp = ppg;                                  // 32 MiB

    pack_w<<<1280, 256, 0, stream>>>(Wt, Wp, Wg, Wo, WcatT, WoT);
    xcast<<<16384, 256, 0, stream>>>(x, xb);
    proj_gemm<<<1536, 256, 0, stream>>>(xb, WcatT, theta, ppg);
    pool_phi<<<4096, 256, 0, stream>>>(ppg, phi);
    pool_gt<<<1024, 256, 0, stream>>>(ppg, gT);
    attn_fused<<<512, 256, 0, stream>>>(theta, phi, gT, tmp);
    out_gemm<<<2048, 256, 0, stream>>>(tmp, WoT, x, gm, out);
}

// Round 3
// 389.704 us; speedup vs baseline: 1.3028x; 1.0533x over previous
//
#include <hip/hip_runtime.h>

typedef __attribute__((ext_vector_type(8))) short bf16x8;
typedef __attribute__((ext_vector_type(4))) float f32x4;
typedef unsigned short u16;
typedef unsigned int u32;

#define MFMA __builtin_amdgcn_mfma_f32_16x16x32_bf16

static __device__ __forceinline__ float b2f(u16 u) {
    u32 x = ((u32)u) << 16;
    return __builtin_bit_cast(float, x);
}
static __device__ __forceinline__ u16 f2b(float f) {
    u32 u = __builtin_bit_cast(u32, f);
    u32 r = (u + 0x7fffu + ((u >> 16) & 1u)) >> 16;
    return (u16)r;
}
// async 16B/lane global->LDS DMA; lds base must be wave-uniform, lane i lands at +i*16
static __device__ __forceinline__ void async16(const u16* g, u16* l) {
    __builtin_amdgcn_global_load_lds(
        (const __attribute__((address_space(1))) u32*)g,
        (__attribute__((address_space(3))) u32*)l, 16, 0, 0);
}

// ---------------- x fp32 -> bf16 ----------------
__global__ __launch_bounds__(256) void xcast(const float* __restrict__ x, u16* __restrict__ xb) {
    size_t i = ((size_t)blockIdx.x * 256 + threadIdx.x) * 8;
    f32x4 f0 = *(const f32x4*)(x + i);
    f32x4 f1 = *(const f32x4*)(x + i + 4);
    bf16x8 v;
    v[0] = (short)f2b(f0[0]); v[1] = (short)f2b(f0[1]);
    v[2] = (short)f2b(f0[2]); v[3] = (short)f2b(f0[3]);
    v[4] = (short)f2b(f1[0]); v[5] = (short)f2b(f1[1]);
    v[6] = (short)f2b(f1[2]); v[7] = (short)f2b(f1[3]);
    *(bf16x8*)(xb + i) = v;
}

// ---------------- weight packing: WcatT[384][512], WoT[512][256] ----------------
__global__ void pack_w(const float* __restrict__ Wt, const float* __restrict__ Wp,
                       const float* __restrict__ Wg, const float* __restrict__ Wo,
                       u16* __restrict__ WcatT, u16* __restrict__ WoT) {
    int t = blockIdx.x * 256 + threadIdx.x;
    const int n1 = 384 * 512;
    if (t < n1) {
        int n = t >> 9, k = t & 511;
        float v;
        if (n < 64)       v = Wt[k * 64 + n];
        else if (n < 128) v = Wp[k * 64 + (n - 64)];
        else              v = Wg[k * 256 + (n - 128)];
        WcatT[t] = f2b(v);
    } else {
        int j = t - n1;
        if (j < 512 * 256) {
            int n = j >> 8, k = j & 255;
            WoT[j] = f2b(Wo[k * 512 + n]);
        }
    }
}

// ---------------- 128x128 GEMM core, 2-phase double-buffered staging ----------------
// S = 32 KiB LDS: buf0 {As 8K | Bs 8K} | buf1 {As 8K | Bs 8K}.
// Per k-step: issue next tile's global_load_lds FIRST, then ds_read+MFMA current tile,
// then one barrier (its vmcnt(0) drain completes the prefetch). One barrier per k-step.
template <int K>
static __device__ __forceinline__ void gemm_core(const u16* __restrict__ A,
                                                 const u16* __restrict__ Bt,
                                                 int m0, int n0, int lda, int ldb,
                                                 f32x4 acc[4][4], u16* S) {
    const int t = threadIdx.x;
    const int w = t >> 6, li = t & 15, quad = (t >> 4) & 3;
    const int wm = (w & 1) << 6, wn = (w >> 1) << 6;
#pragma unroll
    for (int mi = 0; mi < 4; mi++)
#pragma unroll
        for (int ni = 0; ni < 4; ni++) acc[mi][ni] = (f32x4)0.0f;
    const u16* ag = A + (size_t)(m0 + (t >> 2)) * lda + ((t & 3) << 3);
    const u16* bg = Bt + (size_t)(n0 + (t >> 2)) * ldb + ((t & 3) << 3);
    const int ws = w * 512;
    // prologue: stage k-tile 0 into buf 0
    async16(ag, S + ws);
    async16(ag + (size_t)64 * lda, S + ws + 2048);
    async16(bg, S + 4096 + ws);
    async16(bg + (size_t)64 * ldb, S + 4096 + ws + 2048);
    __syncthreads();
    int cur = 0;
#pragma unroll
    for (int k0 = 0; k0 < K; k0 += 32) {
        if (k0 + 32 < K) {
            u16* nS = S + (cur ^ 1) * 8192;
            async16(ag + k0 + 32, nS + ws);
            async16(ag + k0 + 32 + (size_t)64 * lda, nS + ws + 2048);
            async16(bg + k0 + 32, nS + 4096 + ws);
            async16(bg + k0 + 32 + (size_t)64 * ldb, nS + 4096 + ws + 2048);
        }
        const u16* As = S + cur * 8192;
        const u16* Bs = As + 4096;
        bf16x8 af[4], bfr[4];
#pragma unroll
        for (int mi = 0; mi < 4; mi++)
            af[mi] = *(const bf16x8*)(As + (wm + mi * 16 + li) * 32 + quad * 8);
#pragma unroll
        for (int ni = 0; ni < 4; ni++)
            bfr[ni] = *(const bf16x8*)(Bs + (wn + ni * 16 + li) * 32 + quad * 8);
#pragma unroll
        for (int mi = 0; mi < 4; mi++)
#pragma unroll
            for (int ni = 0; ni < 4; ni++)
                acc[mi][ni] = MFMA(af[mi], bfr[ni], acc[mi][ni], 0, 0, 0);
        __syncthreads();  // reads of buf[cur] done; prefetch into buf[cur^1] drained
        cur ^= 1;
    }
}

// per-wave LDS transpose epilogue -> coalesced 16B bf16 stores (64x64 quadrant)
// split into two 32-row halves so ebuf fits in 4 x 4608 B (overlays 32 KiB staging)
static __device__ __forceinline__ void epi_bf16(const f32x4 acc[4][4], u16* ebuf,
                                                u16* __restrict__ outp, int ld,
                                                int row0, int col0) {
    const int t = threadIdx.x;
    const int li = t & 15, quad = (t >> 4) & 3;
    const int rr = (t & 63) >> 3, cc = (t & 7) * 8;
#pragma unroll
    for (int h = 0; h < 2; h++) {
#pragma unroll
        for (int m2 = 0; m2 < 2; m2++)
#pragma unroll
            for (int ni = 0; ni < 4; ni++)
#pragma unroll
                for (int r = 0; r < 4; r++)
                    ebuf[(m2 * 16 + quad * 4 + r) * 72 + ni * 16 + li] =
                        f2b(acc[h * 2 + m2][ni][r]);
        // same-wave LDS write->read is ordered (compiler lgkmcnt)
#pragma unroll
        for (int j = 0; j < 4; j++) {
            int row = j * 8 + rr;
            bf16x8 v = *(const bf16x8*)(ebuf + row * 72 + cc);
            *(bf16x8*)(outp + (size_t)(row0 + h * 32 + row) * ld + col0 + cc) = v;
        }
    }
}

// ---------------- proj: xb[65536x512] @ WcatT -> theta[*,64] + ppg[*,320] ----------------
__global__ __launch_bounds__(256) void proj_gemm(const u16* __restrict__ xb,
                                                 const u16* __restrict__ WcatT,
                                                 u16* __restrict__ theta,
                                                 u16* __restrict__ ppg) {
    __shared__ __attribute__((aligned(16))) u16 sbuf[16384];  // 32 KiB
    int bid = blockIdx.x;
    int sbid = (bid & 7) * 192 + (bid >> 3);   // XCD-aware, bijective (1536 % 8 == 0)
    int bm = sbid / 3, bn = sbid % 3;
    f32x4 acc[4][4];
    gemm_core<512>(xb, WcatT, bm * 128, bn * 128, 512, 512, acc, sbuf);
    const int w = threadIdx.x >> 6;
    u16* ebuf = sbuf + w * 2304;  // 32 x 72 u16 per wave
    int row0 = bm * 128 + (w & 1) * 64;
    int gcol = bn * 128 + (w >> 1) * 64;
    if (gcol < 64) epi_bf16(acc, ebuf, theta, 64, row0, 0);
    else           epi_bf16(acc, ebuf, ppg, 320, row0, gcol - 64);
}

// ---------------- maxpool phi: ppg cols 0..63 -> phi[b][1024][64] ----------------
__global__ void pool_phi(const u16* __restrict__ ppg, u16* __restrict__ phi) {
    int t = blockIdx.x * 256 + threadIdx.x;
    int c = t & 63;
    int pos = (t >> 6) & 1023;
    int b = t >> 16;
    int h2 = pos >> 5, w2 = pos & 31;
    size_t base = ((size_t)(b << 12) + h2 * 128 + w2 * 2) * 320 + c;
    float v0 = b2f(ppg[base]), v1 = b2f(ppg[base + 320]);
    float v2 = b2f(ppg[base + 320 * 64]), v3 = b2f(ppg[base + 320 * 65]);
    float m = fmaxf(fmaxf(v0, v1), fmaxf(v2, v3));
    phi[((size_t)(b << 10) + pos) * 64 + c] = f2b(m);
}

// ---------------- maxpool g, transposed: gT[b][256][1024] ----------------
__global__ void pool_gt(const u16* __restrict__ ppg, u16* __restrict__ gT) {
    __shared__ float tile[64][65];
    int bid = blockIdx.x;
    int b = bid >> 6;
    int rem = bid & 63;
    int c0 = (rem >> 4) * 64;
    int pos0 = (rem & 15) * 64;
    int t = threadIdx.x;
#pragma unroll
    for (int i = 0; i < 16; i++) {
        int o = t + i * 256;
        int cl = o & 63, pl = o >> 6;
        int pos = pos0 + pl;
        int h2 = pos >> 5, w2 = pos & 31;
        size_t base = ((size_t)(b << 12) + h2 * 128 + w2 * 2) * 320 + 64 + c0 + cl;
        float v0 = b2f(ppg[base]), v1 = b2f(ppg[base + 320]);
        float v2 = b2f(ppg[base + 320 * 64]), v3 = b2f(ppg[base + 320 * 65]);
        tile[pl][cl] = fmaxf(fmaxf(v0, v1), fmaxf(v2, v3));
    }
    __syncthreads();
    int cl = t >> 2, ch = t & 3;
    u16 valbuf[16] __attribute__((aligned(16)));
#pragma unroll
    for (int j = 0; j < 16; j++) valbuf[j] = f2b(tile[ch * 16 + j][cl]);
    u16* dst = gT + ((size_t)b * 256 + c0 + cl) * 1024 + pos0 + ch * 16;
    *(uint4*)(dst) = *(const uint4*)(valbuf);
    *(uint4*)(dst + 8) = *(const uint4*)(valbuf + 8);
}

// ---------------- fused attention, QBLK=128, wave-owns-32q (2 x 16q groups) ----------------
__global__ __launch_bounds__(256, 2) void attn_fused(const u16* __restrict__ theta,
                                                     const u16* __restrict__ phi,
                                                     const u16* __restrict__ gT,
                                                     u16* __restrict__ tmp) {
    __shared__ __attribute__((aligned(16))) u16 lds[28672];  // 56 KiB
    u16* stgP = lds;            // [64 key][64 d] swizzled, 8 KiB
    u16* stgG = lds + 4096;     // [256 v][64 k] swizzled, 32 KiB
    u16* pbuf = lds + 20480;    // 4 waves x 2 qg x [16 q][64 k] swizzled, 16 KiB

    int bid = blockIdx.x;
    int swz = (bid & 7) * 64 + (bid >> 3);   // XCD-aware, bijective (512 % 8 == 0)
    int b = swz >> 5;
    int q0 = (swz & 31) << 7;
    const int t = threadIdx.x;
    const int w = t >> 6, li = t & 15, quad = (t >> 4) & 3;

    // theta B-frags for this wave's 32 q rows (q = q0 + w*32 + qg*16 + li)
    const u16* thp = theta + (((size_t)(b << 12) + q0 + w * 32 + li) << 6) + quad * 8;
    bf16x8 tq[2][2];
    tq[0][0] = *(const bf16x8*)thp;
    tq[0][1] = *(const bf16x8*)(thp + 32);
    tq[1][0] = *(const bf16x8*)(thp + (16 << 6));
    tq[1][1] = *(const bf16x8*)(thp + (16 << 6) + 32);

    // DMA source swizzle: LDS slot (row=t>>3 (+32j), pos=t&7) <- global chunk pos^(row&7)
    const int srow = t >> 3;
    const int sc = (t & 7) ^ (srow & 7);
    const u16* phisrc = phi + ((size_t)(b << 10) + srow) * 64 + sc * 8;
    const u16* gsrc = gT + ((size_t)(b << 8) + srow) * 1024 + sc * 8;
    u16* pbq[2] = {pbuf + (w * 2 + 0) * 1024, pbuf + (w * 2 + 1) * 1024};

    f32x4 o[2][16];
#pragma unroll
    for (int qg = 0; qg < 2; qg++)
#pragma unroll
        for (int ni = 0; ni < 16; ni++) o[qg][ni] = (f32x4)0.0f;
    float m[2] = {-3.0e38f, -3.0e38f}, sum[2] = {0.0f, 0.0f};

    for (int kc = 0; kc < 16; kc++) {
        __syncthreads();
        // stage phi chunk (2 shots) + gT chunk (8 shots)
        async16(phisrc + (size_t)(kc * 64) * 64, stgP + w * 512);
        async16(phisrc + (size_t)(kc * 64 + 32) * 64, stgP + 2048 + w * 512);
#pragma unroll
        for (int j = 0; j < 8; j++)
            async16(gsrc + (size_t)(j * 32) * 1024 + kc * 64, stgG + j * 2048 + w * 512);
        __syncthreads();

        // ---- scores (swapped): sacc[qg][nf] = S^T[key = nf*16+quad*4+r][q = li] ----
        f32x4 sacc[2][4];
#pragma unroll
        for (int qg = 0; qg < 2; qg++)
#pragma unroll
            for (int nf = 0; nf < 4; nf++) sacc[qg][nf] = (f32x4)0.0f;
#pragma unroll
        for (int nf = 0; nf < 4; nf++) {
            int row = nf * 16 + li;
            int p0 = quad ^ (li & 7);
            int p1 = (4 + quad) ^ (li & 7);
            bf16x8 f0 = *(const bf16x8*)(stgP + row * 64 + p0 * 8);
            bf16x8 f1 = *(const bf16x8*)(stgP + row * 64 + p1 * 8);
            sacc[0][nf] = MFMA(f0, tq[0][0], sacc[0][nf], 0, 0, 0);
            sacc[0][nf] = MFMA(f1, tq[0][1], sacc[0][nf], 0, 0, 0);
            sacc[1][nf] = MFMA(f0, tq[1][0], sacc[1][nf], 0, 0, 0);
            sacc[1][nf] = MFMA(f1, tq[1][1], sacc[1][nf], 0, 0, 0);
        }

        // ---- online softmax per qg; state per q, q == li for all 4 quad-replicas ----
#pragma unroll
        for (int qg = 0; qg < 2; qg++) {
            float mc = sacc[qg][0][0];
#pragma unroll
            for (int nf = 0; nf < 4; nf++)
#pragma unroll
                for (int r = 0; r < 4; r++) mc = fmaxf(mc, sacc[qg][nf][r]);
            mc = fmaxf(mc, __shfl_xor(mc, 16, 64));
            mc = fmaxf(mc, __shfl_xor(mc, 32, 64));
            if (!__all(mc <= m[qg] + 8.0f)) {   // defer-max: rescale only on real growth
                float nm = fmaxf(m[qg], mc);
                float f = __expf(m[qg] - nm);
                sum[qg] *= f;
#pragma unroll
                for (int ni = 0; ni < 16; ni++)
#pragma unroll
                    for (int r = 0; r < 4; r++) o[qg][ni][r] *= f;
                m[qg] = nm;
            }
            float p[16];
            float s = 0.0f;
#pragma unroll
            for (int nf = 0; nf < 4; nf++)
#pragma unroll
                for (int r = 0; r < 4; r++) {
                    float e = __expf(sacc[qg][nf][r] - m[qg]);
                    p[nf * 4 + r] = e;
                    s += e;
                }
            s += __shfl_xor(s, 16, 64);
            s += __shfl_xor(s, 32, 64);
            sum[qg] += s;

            // ---- P -> wave-private LDS (bf16 pairs, XOR chunk swizzle) ----
            u16* pb = pbq[qg];
#pragma unroll
            for (int nf = 0; nf < 4; nf++) {
                int cc = nf * 2 + (quad >> 1);
                int pos = cc ^ (li & 7);
                u32* dst = (u32*)(pb + li * 64 + pos * 8 + (quad & 1) * 4);
                dst[0] = (u32)f2b(p[nf * 4 + 0]) | ((u32)f2b(p[nf * 4 + 1]) << 16);
                dst[1] = (u32)f2b(p[nf * 4 + 2]) | ((u32)f2b(p[nf * 4 + 3]) << 16);
            }
        }

        // ---- PV: o[qg][ni] += mfma(A=g, B=P_qg); g frag read once, used twice ----
#pragma unroll
        for (int w2 = 0; w2 < 2; w2++) {
            int pos8 = ((w2 * 4 + quad) ^ (li & 7)) * 8;
            bf16x8 pf0 = *(const bf16x8*)(pbq[0] + li * 64 + pos8);
            bf16x8 pf1 = *(const bf16x8*)(pbq[1] + li * 64 + pos8);
#pragma unroll
            for (int ni = 0; ni < 16; ni++) {
                bf16x8 gf = *(const bf16x8*)(stgG + (ni * 16 + li) * 64 + pos8);
                o[0][ni] = MFMA(gf, pf0, o[0][ni], 0, 0, 0);
                o[1][ni] = MFMA(gf, pf1, o[1][ni], 0, 0, 0);
            }
        }
    }

    // ---- normalize (1/sum is scalar per lane: q == li) ----
    float inv[2] = {1.0f / sum[0], 1.0f / sum[1]};
#pragma unroll
    for (int qg = 0; qg < 2; qg++)
#pragma unroll
        for (int ni = 0; ni < 16; ni++)
#pragma unroll
            for (int r = 0; r < 4; r++) o[qg][ni][r] *= inv[qg];

    // ---- epilogue: per-wave transpose O^T[v][q] -> tmp[q][256v], coalesced 16B stores ----
    __syncthreads();  // all waves done reading stgP/stgG
    u16* eb = lds + w * 4224;  // 16 q rows x 264 elems (padded), reused per qg
    const int lane = t & 63;
#pragma unroll
    for (int qg = 0; qg < 2; qg++) {
#pragma unroll
        for (int ni = 0; ni < 16; ni++) {
            u32* d = (u32*)(eb + li * 264 + ni * 16 + quad * 4);
            d[0] = (u32)f2b(o[qg][ni][0]) | ((u32)f2b(o[qg][ni][1]) << 16);
            d[1] = (u32)f2b(o[qg][ni][2]) | ((u32)f2b(o[qg][ni][3]) << 16);
        }
#pragma unroll
        for (int pss = 0; pss < 8; pss++) {
            int row = pss * 2 + (lane >> 5);
            bf16x8 v = *(const bf16x8*)(eb + row * 264 + (lane & 31) * 8);
            *(bf16x8*)(tmp + ((size_t)(b << 12) + q0 + w * 32 + qg * 16 + row) * 256 +
                       (lane & 31) * 8) = v;
        }
    }
}

// ---------------- out: tmp[65536x256] @ WoT + gamma*o + x (fp32) ----------------
__global__ __launch_bounds__(256) void out_gemm(const u16* __restrict__ tmp,
                                                const u16* __restrict__ WoT,
                                                const float* __restrict__ x,
                                                const float* __restrict__ gamma_p,
                                                float* __restrict__ out) {
    __shared__ __attribute__((aligned(16))) u16 sbuf[16384];  // 32 KiB
    int bid = blockIdx.x;
    int sbid = (bid & 7) * 256 + (bid >> 3);   // XCD-aware, bijective (2048 % 8 == 0)
    int bm = sbid >> 2, bn = sbid & 3;
    f32x4 acc[4][4];
    gemm_core<256>(tmp, WoT, bm * 128, bn * 128, 256, 256, acc, sbuf);
    float gamma = gamma_p[0];
    const int t = threadIdx.x;
    const int w = t >> 6, li = t & 15, quad = (t >> 4) & 3;
    int row0 = bm * 128 + (w & 1) * 64;
    int col0 = bn * 128 + (w >> 1) * 64;
    float* fb = (float*)sbuf + w * 1088;  // 16 x 68 fp32 per wave (4352 B)
    const int lane = t & 63;
    const int rhi = lane >> 4, cl = (lane & 15) * 4;
    // 4 passes of 16-row stripes: prefetch x into regs, LDS-transpose, fused store
#pragma unroll
    for (int mi = 0; mi < 4; mi++) {
        f32x4 xv[4];
#pragma unroll
        for (int j = 0; j < 4; j++) {
            size_t go = (size_t)(row0 + mi * 16 + j * 4 + rhi) * 512 + col0 + cl;
            xv[j] = *(const f32x4*)(x + go);
        }
#pragma unroll
        for (int ni = 0; ni < 4; ni++)
#pragma unroll
            for (int r = 0; r < 4; r++)
                fb[(quad * 4 + r) * 68 + ni * 16 + li] = acc[mi][ni][r];
        // same-wave LDS write->read is ordered (compiler lgkmcnt)
#pragma unroll
        for (int j = 0; j < 4; j++) {
            f32x4 v = *(const f32x4*)(fb + (j * 4 + rhi) * 68 + cl);
#pragma unroll
            for (int e = 0; e < 4; e++) v[e] = gamma * v[e] + xv[j][e];
            size_t go = (size_t)(row0 + mi * 16 + j * 4 + rhi) * 512 + col0 + cl;
            *(f32x4*)(out + go) = v;
        }
    }
}

extern "C" void kernel_launch(void* const* d_in, const int* in_sizes, int n_in,
                              void* d_out, int out_size, void* d_ws, size_t ws_size,
                              hipStream_t stream) {
    (void)in_sizes; (void)n_in; (void)out_size; (void)ws_size;
    const float* x  = (const float*)d_in[0];
    const float* Wt = (const float*)d_in[1];
    const float* Wp = (const float*)d_in[2];
    const float* Wg = (const float*)d_in[3];
    const float* Wo = (const float*)d_in[4];
    const float* gm = (const float*)d_in[5];
    float* out = (float*)d_out;

    char* ws = (char*)d_ws;
    size_t off = 0;
    u16* WcatT = (u16*)(ws + off); off += (size_t)384 * 512 * 2;
    u16* WoT   = (u16*)(ws + off); off += (size_t)512 * 256 * 2;
    u16* xb    = (u16*)(ws + off); off += (size_t)65536 * 512 * 2;   // 64 MiB
    u16* theta = (u16*)(ws + off); off += (size_t)65536 * 64 * 2;    // 8 MiB
    u16* ppg   = (u16*)(ws + off); off += (size_t)65536 * 320 * 2;   // 40 MiB
    // aliases: xb dead after proj -> phi/gT live there; ppg dead after pools -> tmp
    u16* phi = xb;                                   // 2 MiB
    u16* gT  = xb + (size_t)16 * 1024 * 64;          // 8 MiB
    u16* tmp = ppg;                                  // 32 MiB

    pack_w<<<1280, 256, 0, stream>>>(Wt, Wp, Wg, Wo, WcatT, WoT);
    xcast<<<16384, 256, 0, stream>>>(x, xb);
    proj_gemm<<<1536, 256, 0, stream>>>(xb, WcatT, theta, ppg);
    pool_phi<<<4096, 256, 0, stream>>>(ppg, phi);
    pool_gt<<<1024, 256, 0, stream>>>(ppg, gT);
    attn_fused<<<512, 256, 0, stream>>>(theta, phi, gT, tmp);
    out_gemm<<<2048, 256, 0, stream>>>(tmp, WoT, x, gm, out);
}

// Round 4
// 356.575 us; speedup vs baseline: 1.4239x; 1.0929x over previous
//
#include <hip/hip_runtime.h>

typedef __attribute__((ext_vector_type(8))) short bf16x8;
typedef __attribute__((ext_vector_type(4))) float f32x4;
typedef unsigned short u16;
typedef unsigned int u32;

#define MFMA __builtin_amdgcn_mfma_f32_16x16x32_bf16

static __device__ __forceinline__ float b2f(u16 u) {
    u32 x = ((u32)u) << 16;
    return __builtin_bit_cast(float, x);
}
static __device__ __forceinline__ u16 f2b(float f) {
    u32 u = __builtin_bit_cast(u32, f);
    u32 r = (u + 0x7fffu + ((u >> 16) & 1u)) >> 16;
    return (u16)r;
}
// async 16B/lane global->LDS DMA; lds base must be wave-uniform, lane i lands at +i*16
static __device__ __forceinline__ void async16(const u16* g, u16* l) {
    __builtin_amdgcn_global_load_lds(
        (const __attribute__((address_space(1))) u32*)g,
        (__attribute__((address_space(3))) u32*)l, 16, 0, 0);
}

// ---------------- weight packing: WcatT[384][512], WoT[512][256] ----------------
__global__ void pack_w(const float* __restrict__ Wt, const float* __restrict__ Wp,
                       const float* __restrict__ Wg, const float* __restrict__ Wo,
                       u16* __restrict__ WcatT, u16* __restrict__ WoT) {
    int t = blockIdx.x * 256 + threadIdx.x;
    const int n1 = 384 * 512;
    if (t < n1) {
        int n = t >> 9, k = t & 511;
        float v;
        if (n < 64)       v = Wt[k * 64 + n];
        else if (n < 128) v = Wp[k * 64 + (n - 64)];
        else              v = Wg[k * 256 + (n - 128)];
        WcatT[t] = f2b(v);
    } else {
        int j = t - n1;
        if (j < 512 * 256) {
            int n = j >> 8, k = j & 255;
            WoT[j] = f2b(Wo[k * 512 + n]);
        }
    }
}

// ---------------- 128x128 GEMM core (bf16 A), 2-phase double-buffered ----------------
template <int K>
static __device__ __forceinline__ void gemm_core(const u16* __restrict__ A,
                                                 const u16* __restrict__ Bt,
                                                 int m0, int n0, int lda, int ldb,
                                                 f32x4 acc[4][4], u16* S) {
    const int t = threadIdx.x;
    const int w = t >> 6, li = t & 15, quad = (t >> 4) & 3;
    const int wm = (w & 1) << 6, wn = (w >> 1) << 6;
#pragma unroll
    for (int mi = 0; mi < 4; mi++)
#pragma unroll
        for (int ni = 0; ni < 4; ni++) acc[mi][ni] = (f32x4)0.0f;
    const u16* ag = A + (size_t)(m0 + (t >> 2)) * lda + ((t & 3) << 3);
    const u16* bg = Bt + (size_t)(n0 + (t >> 2)) * ldb + ((t & 3) << 3);
    const int ws = w * 512;
    async16(ag, S + ws);
    async16(ag + (size_t)64 * lda, S + ws + 2048);
    async16(bg, S + 4096 + ws);
    async16(bg + (size_t)64 * ldb, S + 4096 + ws + 2048);
    __syncthreads();
    int cur = 0;
#pragma unroll
    for (int k0 = 0; k0 < K; k0 += 32) {
        if (k0 + 32 < K) {
            u16* nS = S + (cur ^ 1) * 8192;
            async16(ag + k0 + 32, nS + ws);
            async16(ag + k0 + 32 + (size_t)64 * lda, nS + ws + 2048);
            async16(bg + k0 + 32, nS + 4096 + ws);
            async16(bg + k0 + 32 + (size_t)64 * ldb, nS + 4096 + ws + 2048);
        }
        const u16* As = S + cur * 8192;
        const u16* Bs = As + 4096;
        bf16x8 af[4], bfr[4];
#pragma unroll
        for (int mi = 0; mi < 4; mi++)
            af[mi] = *(const bf16x8*)(As + (wm + mi * 16 + li) * 32 + quad * 8);
#pragma unroll
        for (int ni = 0; ni < 4; ni++)
            bfr[ni] = *(const bf16x8*)(Bs + (wn + ni * 16 + li) * 32 + quad * 8);
#pragma unroll
        for (int mi = 0; mi < 4; mi++)
#pragma unroll
            for (int ni = 0; ni < 4; ni++)
                acc[mi][ni] = MFMA(af[mi], bfr[ni], acc[mi][ni], 0, 0, 0);
        __syncthreads();
        cur ^= 1;
    }
}

// ---------------- 128x128 GEMM core, A = fp32 global (reg-staged cast), B bf16 ----------
// ds_write dest (S + t*8 u16) is byte-identical to what async16 would produce, so the
// MFMA-facing LDS layout is unchanged. Next-tile global loads issue BEFORE the MFMAs.
template <int K>
static __device__ __forceinline__ void gemm_core_f32(const float* __restrict__ A,
                                                     const u16* __restrict__ Bt,
                                                     int m0, int n0, int lda, int ldb,
                                                     f32x4 acc[4][4], u16* S) {
    const int t = threadIdx.x;
    const int w = t >> 6, li = t & 15, quad = (t >> 4) & 3;
    const int wm = (w & 1) << 6, wn = (w >> 1) << 6;
#pragma unroll
    for (int mi = 0; mi < 4; mi++)
#pragma unroll
        for (int ni = 0; ni < 4; ni++) acc[mi][ni] = (f32x4)0.0f;
    const float* ag = A + (size_t)(m0 + (t >> 2)) * lda + ((t & 3) << 3);
    const u16* bg = Bt + (size_t)(n0 + (t >> 2)) * ldb + ((t & 3) << 3);
    const int ws = w * 512;
    // prologue: tile 0
    {
        f32x4 a00 = *(const f32x4*)(ag);
        f32x4 a01 = *(const f32x4*)(ag + 4);
        f32x4 a10 = *(const f32x4*)(ag + (size_t)64 * lda);
        f32x4 a11 = *(const f32x4*)(ag + (size_t)64 * lda + 4);
        async16(bg, S + 4096 + ws);
        async16(bg + (size_t)64 * ldb, S + 4096 + ws + 2048);
        bf16x8 v0, v1;
#pragma unroll
        for (int e = 0; e < 4; e++) {
            v0[e] = (short)f2b(a00[e]); v0[4 + e] = (short)f2b(a01[e]);
            v1[e] = (short)f2b(a10[e]); v1[4 + e] = (short)f2b(a11[e]);
        }
        *(bf16x8*)(S + t * 8) = v0;
        *(bf16x8*)(S + 2048 + t * 8) = v1;
    }
    __syncthreads();
    int cur = 0;
#pragma unroll
    for (int k0 = 0; k0 < K; k0 += 32) {
        f32x4 a00, a01, a10, a11;
        if (k0 + 32 < K) {
            a00 = *(const f32x4*)(ag + k0 + 32);
            a01 = *(const f32x4*)(ag + k0 + 36);
            a10 = *(const f32x4*)(ag + k0 + 32 + (size_t)64 * lda);
            a11 = *(const f32x4*)(ag + k0 + 36 + (size_t)64 * lda);
            u16* nS = S + (cur ^ 1) * 8192;
            async16(bg + k0 + 32, nS + 4096 + ws);
            async16(bg + k0 + 32 + (size_t)64 * ldb, nS + 4096 + ws + 2048);
        }
        const u16* As = S + cur * 8192;
        const u16* Bs = As + 4096;
        bf16x8 af[4], bfr[4];
#pragma unroll
        for (int mi = 0; mi < 4; mi++)
            af[mi] = *(const bf16x8*)(As + (wm + mi * 16 + li) * 32 + quad * 8);
#pragma unroll
        for (int ni = 0; ni < 4; ni++)
            bfr[ni] = *(const bf16x8*)(Bs + (wn + ni * 16 + li) * 32 + quad * 8);
#pragma unroll
        for (int mi = 0; mi < 4; mi++)
#pragma unroll
            for (int ni = 0; ni < 4; ni++)
                acc[mi][ni] = MFMA(af[mi], bfr[ni], acc[mi][ni], 0, 0, 0);
        if (k0 + 32 < K) {
            u16* nS = S + (cur ^ 1) * 8192;
            bf16x8 v0, v1;
#pragma unroll
            for (int e = 0; e < 4; e++) {
                v0[e] = (short)f2b(a00[e]); v0[4 + e] = (short)f2b(a01[e]);
                v1[e] = (short)f2b(a10[e]); v1[4 + e] = (short)f2b(a11[e]);
            }
            *(bf16x8*)(nS + t * 8) = v0;
            *(bf16x8*)(nS + 2048 + t * 8) = v1;
        }
        __syncthreads();
        cur ^= 1;
    }
}

// ---------------- proj: x[65536x512] @ WcatT -> theta + pooled phi + pooled gT ----------
// Block (bm, bn) owns rows bm*128 (= batch b=bm>>5, h={2*(bm&31), +1}, all w) and output
// cols bn*128 of 384. Pooling is block-local: pooled pos2 = (bm&31)*32 + w2.
// Epilogue: full 128x128 bf16 tile -> LDS (chunk-XOR swizzle), then per-bn emit.
__global__ __launch_bounds__(256) void proj_gemm(const float* __restrict__ x,
                                                 const u16* __restrict__ WcatT,
                                                 u16* __restrict__ theta,
                                                 u16* __restrict__ phi,
                                                 u16* __restrict__ gT) {
    __shared__ __attribute__((aligned(16))) u16 S[16384];  // 32 KiB
    int bid = blockIdx.x;
    int sbid = (bid & 7) * 192 + (bid >> 3);   // XCD-aware, bijective (1536 % 8 == 0)
    int bm = sbid / 3, bn = sbid % 3;
    int m0 = bm * 128;
    f32x4 acc[4][4];
    gemm_core_f32<512>(x, WcatT, m0, bn * 128, 512, 512, acc, S);

    const int t = threadIdx.x;
    const int w = t >> 6, li = t & 15, quad = (t >> 4) & 3;
    // ---- write full tile L[lr][c] swizzled: u16 idx = lr*128 + ((c>>3)^(lr&7))*8 + (c&7)
    const int cbase = (w >> 1) << 6;
    const int rbase = (w & 1) << 6;
#pragma unroll
    for (int mi = 0; mi < 4; mi++)
#pragma unroll
        for (int ni = 0; ni < 4; ni++) {
            int c = cbase + ni * 16 + li;
            int ch = c >> 3, ce = c & 7;
#pragma unroll
            for (int r = 0; r < 4; r++) {
                int lr = rbase + mi * 16 + quad * 4 + r;
                S[lr * 128 + ((ch ^ (lr & 7)) << 3) + ce] = f2b(acc[mi][ni][r]);
            }
        }
    __syncthreads();

    const int b = bm >> 5;
    if (bn == 0) {
        // theta: rows all, cols 0..63 (unpooled)
        int lr = t >> 1;
#pragma unroll
        for (int k = 0; k < 4; k++) {
            int ch = (t & 1) * 4 + k;
            bf16x8 v = *(const bf16x8*)(S + lr * 128 + ((ch ^ (lr & 7)) << 3));
            *(bf16x8*)(theta + (size_t)(m0 + lr) * 64 + (t & 1) * 32 + k * 8) = v;
        }
        // phi: cols 64..127 pooled -> phi[b][pos2][64]
        int w2 = t >> 3;
        int chp = 8 + (t & 7);
        int r0 = 2 * w2, r1 = r0 + 1, r2 = r0 + 64, r3 = r0 + 65;
        bf16x8 v0 = *(const bf16x8*)(S + r0 * 128 + ((chp ^ (r0 & 7)) << 3));
        bf16x8 v1 = *(const bf16x8*)(S + r1 * 128 + ((chp ^ (r1 & 7)) << 3));
        bf16x8 v2 = *(const bf16x8*)(S + r2 * 128 + ((chp ^ (r2 & 7)) << 3));
        bf16x8 v3 = *(const bf16x8*)(S + r3 * 128 + ((chp ^ (r3 & 7)) << 3));
        bf16x8 pv;
#pragma unroll
        for (int e = 0; e < 8; e++) {
            float mv = fmaxf(fmaxf(b2f((u16)v0[e]), b2f((u16)v1[e])),
                             fmaxf(b2f((u16)v2[e]), b2f((u16)v3[e])));
            pv[e] = (short)f2b(mv);
        }
        int pos2 = (bm & 31) * 32 + w2;
        *(bf16x8*)(phi + ((size_t)(b << 10) + pos2) * 64 + (t & 7) * 8) = pv;
    } else {
        // gT pooled + transposed: thread owns channel c = t>>1, 16 pos2 values
        const int c = t >> 1;
        const int poff = (t & 1) * 16;
        const int ch = c >> 3, ce = c & 7;
        u16 vals[16] __attribute__((aligned(16)));
#pragma unroll
        for (int j = 0; j < 16; j++) {
            int w2 = poff + j;
            int r0 = 2 * w2, r1 = r0 + 1, r2 = r0 + 64, r3 = r0 + 65;
            float m0v = b2f(S[r0 * 128 + ((ch ^ (r0 & 7)) << 3) + ce]);
            float m1v = b2f(S[r1 * 128 + ((ch ^ (r1 & 7)) << 3) + ce]);
            float m2v = b2f(S[r2 * 128 + ((ch ^ (r2 & 7)) << 3) + ce]);
            float m3v = b2f(S[r3 * 128 + ((ch ^ (r3 & 7)) << 3) + ce]);
            vals[j] = f2b(fmaxf(fmaxf(m0v, m1v), fmaxf(m2v, m3v)));
        }
        int cg = (bn - 1) * 128 + c;
        int pos2b = (bm & 31) * 32 + poff;
        u16* dst = gT + ((size_t)(b << 8) + cg) * 1024 + pos2b;
        *(uint4*)dst = *(const uint4*)vals;
        *(uint4*)(dst + 8) = *(const uint4*)(vals + 8);
    }
}

// ---------------- fused attention, QBLK=128, wave-owns-32q (2 x 16q groups) ----------------
__global__ __launch_bounds__(256, 2) void attn_fused(const u16* __restrict__ theta,
                                                     const u16* __restrict__ phi,
                                                     const u16* __restrict__ gT,
                                                     u16* __restrict__ tmp) {
    __shared__ __attribute__((aligned(16))) u16 lds[28672];  // 56 KiB
    u16* stgP = lds;            // [64 key][64 d] swizzled, 8 KiB
    u16* stgG = lds + 4096;     // [256 v][64 k] swizzled, 32 KiB
    u16* pbuf = lds + 20480;    // 4 waves x 2 qg x [16 q][64 k] swizzled, 16 KiB

    int bid = blockIdx.x;
    int swz = (bid & 7) * 64 + (bid >> 3);   // XCD-aware, bijective (512 % 8 == 0)
    int b = swz >> 5;
    int q0 = (swz & 31) << 7;
    const int t = threadIdx.x;
    const int w = t >> 6, li = t & 15, quad = (t >> 4) & 3;

    const u16* thp = theta + (((size_t)(b << 12) + q0 + w * 32 + li) << 6) + quad * 8;
    bf16x8 tq[2][2];
    tq[0][0] = *(const bf16x8*)thp;
    tq[0][1] = *(const bf16x8*)(thp + 32);
    tq[1][0] = *(const bf16x8*)(thp + (16 << 6));
    tq[1][1] = *(const bf16x8*)(thp + (16 << 6) + 32);

    const int srow = t >> 3;
    const int sc = (t & 7) ^ (srow & 7);
    const u16* phisrc = phi + ((size_t)(b << 10) + srow) * 64 + sc * 8;
    const u16* gsrc = gT + ((size_t)(b << 8) + srow) * 1024 + sc * 8;
    u16* pbq[2] = {pbuf + (w * 2 + 0) * 1024, pbuf + (w * 2 + 1) * 1024};

    f32x4 o[2][16];
#pragma unroll
    for (int qg = 0; qg < 2; qg++)
#pragma unroll
        for (int ni = 0; ni < 16; ni++) o[qg][ni] = (f32x4)0.0f;
    float m[2] = {-3.0e38f, -3.0e38f}, sum[2] = {0.0f, 0.0f};

    for (int kc = 0; kc < 16; kc++) {
        __syncthreads();
        async16(phisrc + (size_t)(kc * 64) * 64, stgP + w * 512);
        async16(phisrc + (size_t)(kc * 64 + 32) * 64, stgP + 2048 + w * 512);
#pragma unroll
        for (int j = 0; j < 8; j++)
            async16(gsrc + (size_t)(j * 32) * 1024 + kc * 64, stgG + j * 2048 + w * 512);
        __syncthreads();

        f32x4 sacc[2][4];
#pragma unroll
        for (int qg = 0; qg < 2; qg++)
#pragma unroll
            for (int nf = 0; nf < 4; nf++) sacc[qg][nf] = (f32x4)0.0f;
#pragma unroll
        for (int nf = 0; nf < 4; nf++) {
            int row = nf * 16 + li;
            int p0 = quad ^ (li & 7);
            int p1 = (4 + quad) ^ (li & 7);
            bf16x8 f0 = *(const bf16x8*)(stgP + row * 64 + p0 * 8);
            bf16x8 f1 = *(const bf16x8*)(stgP + row * 64 + p1 * 8);
            sacc[0][nf] = MFMA(f0, tq[0][0], sacc[0][nf], 0, 0, 0);
            sacc[0][nf] = MFMA(f1, tq[0][1], sacc[0][nf], 0, 0, 0);
            sacc[1][nf] = MFMA(f0, tq[1][0], sacc[1][nf], 0, 0, 0);
            sacc[1][nf] = MFMA(f1, tq[1][1], sacc[1][nf], 0, 0, 0);
        }

#pragma unroll
        for (int qg = 0; qg < 2; qg++) {
            float mc = sacc[qg][0][0];
#pragma unroll
            for (int nf = 0; nf < 4; nf++)
#pragma unroll
                for (int r = 0; r < 4; r++) mc = fmaxf(mc, sacc[qg][nf][r]);
            mc = fmaxf(mc, __shfl_xor(mc, 16, 64));
            mc = fmaxf(mc, __shfl_xor(mc, 32, 64));
            if (!__all(mc <= m[qg] + 8.0f)) {
                float nm = fmaxf(m[qg], mc);
                float f = __expf(m[qg] - nm);
                sum[qg] *= f;
#pragma unroll
                for (int ni = 0; ni < 16; ni++)
#pragma unroll
                    for (int r = 0; r < 4; r++) o[qg][ni][r] *= f;
                m[qg] = nm;
            }
            float p[16];
            float s = 0.0f;
#pragma unroll
            for (int nf = 0; nf < 4; nf++)
#pragma unroll
                for (int r = 0; r < 4; r++) {
                    float e = __expf(sacc[qg][nf][r] - m[qg]);
                    p[nf * 4 + r] = e;
                    s += e;
                }
            s += __shfl_xor(s, 16, 64);
            s += __shfl_xor(s, 32, 64);
            sum[qg] += s;

            u16* pb = pbq[qg];
#pragma unroll
            for (int nf = 0; nf < 4; nf++) {
                int cc = nf * 2 + (quad >> 1);
                int pos = cc ^ (li & 7);
                u32* dst = (u32*)(pb + li * 64 + pos * 8 + (quad & 1) * 4);
                dst[0] = (u32)f2b(p[nf * 4 + 0]) | ((u32)f2b(p[nf * 4 + 1]) << 16);
                dst[1] = (u32)f2b(p[nf * 4 + 2]) | ((u32)f2b(p[nf * 4 + 3]) << 16);
            }
        }

#pragma unroll
        for (int w2 = 0; w2 < 2; w2++) {
            int pos8 = ((w2 * 4 + quad) ^ (li & 7)) * 8;
            bf16x8 pf0 = *(const bf16x8*)(pbq[0] + li * 64 + pos8);
            bf16x8 pf1 = *(const bf16x8*)(pbq[1] + li * 64 + pos8);
#pragma unroll
            for (int ni = 0; ni < 16; ni++) {
                bf16x8 gf = *(const bf16x8*)(stgG + (ni * 16 + li) * 64 + pos8);
                o[0][ni] = MFMA(gf, pf0, o[0][ni], 0, 0, 0);
                o[1][ni] = MFMA(gf, pf1, o[1][ni], 0, 0, 0);
            }
        }
    }

    float inv[2] = {1.0f / sum[0], 1.0f / sum[1]};
#pragma unroll
    for (int qg = 0; qg < 2; qg++)
#pragma unroll
        for (int ni = 0; ni < 16; ni++)
#pragma unroll
            for (int r = 0; r < 4; r++) o[qg][ni][r] *= inv[qg];

    __syncthreads();
    u16* eb = lds + w * 4224;
    const int lane = t & 63;
#pragma unroll
    for (int qg = 0; qg < 2; qg++) {
#pragma unroll
        for (int ni = 0; ni < 16; ni++) {
            u32* d = (u32*)(eb + li * 264 + ni * 16 + quad * 4);
            d[0] = (u32)f2b(o[qg][ni][0]) | ((u32)f2b(o[qg][ni][1]) << 16);
            d[1] = (u32)f2b(o[qg][ni][2]) | ((u32)f2b(o[qg][ni][3]) << 16);
        }
#pragma unroll
        for (int pss = 0; pss < 8; pss++) {
            int row = pss * 2 + (lane >> 5);
            bf16x8 v = *(const bf16x8*)(eb + row * 264 + (lane & 31) * 8);
            *(bf16x8*)(tmp + ((size_t)(b << 12) + q0 + w * 32 + qg * 16 + row) * 256 +
                       (lane & 31) * 8) = v;
        }
    }
}

// ---------------- out: tmp[65536x256] @ WoT + gamma*o + x (fp32) ----------------
__global__ __launch_bounds__(256) void out_gemm(const u16* __restrict__ tmp,
                                                const u16* __restrict__ WoT,
                                                const float* __restrict__ x,
                                                const float* __restrict__ gamma_p,
                                                float* __restrict__ out) {
    __shared__ __attribute__((aligned(16))) u16 sbuf[16384];  // 32 KiB
    int bid = blockIdx.x;
    int sbid = (bid & 7) * 256 + (bid >> 3);   // XCD-aware, bijective (2048 % 8 == 0)
    int bm = sbid >> 2, bn = sbid & 3;
    f32x4 acc[4][4];
    gemm_core<256>(tmp, WoT, bm * 128, bn * 128, 256, 256, acc, sbuf);
    float gamma = gamma_p[0];
    const int t = threadIdx.x;
    const int w = t >> 6, li = t & 15, quad = (t >> 4) & 3;
    int row0 = bm * 128 + (w & 1) * 64;
    int col0 = bn * 128 + (w >> 1) * 64;
    float* fb = (float*)sbuf + w * 1088;  // 16 x 68 fp32 per wave (4352 B)
    const int lane = t & 63;
    const int rhi = lane >> 4, cl = (lane & 15) * 4;
#pragma unroll
    for (int mi = 0; mi < 4; mi++) {
        f32x4 xv[4];
#pragma unroll
        for (int j = 0; j < 4; j++) {
            size_t go = (size_t)(row0 + mi * 16 + j * 4 + rhi) * 512 + col0 + cl;
            xv[j] = *(const f32x4*)(x + go);
        }
#pragma unroll
        for (int ni = 0; ni < 4; ni++)
#pragma unroll
            for (int r = 0; r < 4; r++)
                fb[(quad * 4 + r) * 68 + ni * 16 + li] = acc[mi][ni][r];
#pragma unroll
        for (int j = 0; j < 4; j++) {
            f32x4 v = *(const f32x4*)(fb + (j * 4 + rhi) * 68 + cl);
#pragma unroll
            for (int e = 0; e < 4; e++) v[e] = gamma * v[e] + xv[j][e];
            size_t go = (size_t)(row0 + mi * 16 + j * 4 + rhi) * 512 + col0 + cl;
            *(f32x4*)(out + go) = v;
        }
    }
}

extern "C" void kernel_launch(void* const* d_in, const int* in_sizes, int n_in,
                              void* d_out, int out_size, void* d_ws, size_t ws_size,
                              hipStream_t stream) {
    (void)in_sizes; (void)n_in; (void)out_size; (void)ws_size;
    const float* x  = (const float*)d_in[0];
    const float* Wt = (const float*)d_in[1];
    const float* Wp = (const float*)d_in[2];
    const float* Wg = (const float*)d_in[3];
    const float* Wo = (const float*)d_in[4];
    const float* gm = (const float*)d_in[5];
    float* out = (float*)d_out;

    char* ws = (char*)d_ws;
    size_t off = 0;
    u16* WcatT = (u16*)(ws + off); off += (size_t)384 * 512 * 2;
    u16* WoT   = (u16*)(ws + off); off += (size_t)512 * 256 * 2;
    u16* phi   = (u16*)(ws + off); off += (size_t)16 * 1024 * 64 * 2;   // 2 MiB
    u16* gT    = (u16*)(ws + off); off += (size_t)16 * 256 * 1024 * 2;  // 8 MiB
    u16* theta = (u16*)(ws + off); off += (size_t)65536 * 64 * 2;       // 8 MiB
    u16* tmp   = (u16*)(ws + off); off += (size_t)65536 * 256 * 2;      // 32 MiB

    pack_w<<<1280, 256, 0, stream>>>(Wt, Wp, Wg, Wo, WcatT, WoT);
    proj_gemm<<<1536, 256, 0, stream>>>(x, WcatT, theta, phi, gT);
    attn_fused<<<512, 256, 0, stream>>>(theta, phi, gT, tmp);
    out_gemm<<<2048, 256, 0, stream>>>(tmp, WoT, x, gm, out);
}